// Round 1
// baseline (750.810 us; speedup 1.0000x reference)
//
#include <hip/hip_runtime.h>
#include <hip/hip_bf16.h>

#define B_ 64
#define S_ 1024
#define H_ 1024
#define M_ (B_*S_)   // 65536 rows of the big GEMM

typedef __attribute__((ext_vector_type(8))) short short8;
typedef __attribute__((ext_vector_type(4))) float f32x4;

__device__ __forceinline__ unsigned short f2bf(float f) {
    union { float f; unsigned u; } c; c.f = f;
    unsigned u = c.u;
    unsigned r = (u + 0x7fffu + ((u >> 16) & 1u)) >> 16;  // RTNE, finite inputs
    return (unsigned short)r;
}

__device__ __forceinline__ float tanh_fast(float x) {
    float t = __expf(2.0f * x);                 // exp(2x)
    return 1.0f - 2.0f * __builtin_amdgcn_rcpf(t + 1.0f);  // inf-safe: t=inf -> 1, t=0 -> -1
}

// ---------------------------------------------------------------------------
// K1: proj_s[b,k] = sum_h dec[b,h] * W_s[k,h].  One wave per k-column.
// ---------------------------------------------------------------------------
__global__ void proj_s_kernel(const float* __restrict__ dec,
                              const float* __restrict__ Ws,
                              float* __restrict__ proj_s) {
    const int t = threadIdx.x;
    const int lane = t & 63;
    const int w = t >> 6;
    const int k = blockIdx.x * 4 + w;

    float acc[64];
#pragma unroll
    for (int b = 0; b < 64; ++b) acc[b] = 0.0f;

    for (int hc = 0; hc < 16; ++hc) {
        float wv = Ws[(size_t)k * H_ + hc * 64 + lane];
#pragma unroll
        for (int b = 0; b < 64; ++b)
            acc[b] = fmaf(dec[b * H_ + hc * 64 + lane], wv, acc[b]);
    }
    // full butterfly allreduce: every lane ends with total for every b
#pragma unroll
    for (int m = 1; m < 64; m <<= 1) {
#pragma unroll
        for (int b = 0; b < 64; ++b)
            acc[b] += __shfl_xor(acc[b], m, 64);
    }
    float out = 0.0f;
#pragma unroll
    for (int b = 0; b < 64; ++b)
        if (lane == b) out = acc[b];
    proj_s[lane * H_ + k] = out;
}

// ---------------------------------------------------------------------------
// K2: fused proj_h GEMM (bf16 MFMA) + tanh + v-dot -> scores partials.
// Tile 128x128, BK=32, 4 waves. A = enc [M_,K], B = W_h [N,K] (both K-contig).
// scores_part[nt][m] = sum over this N-tile's 128 cols of tanh(.)*v
// ---------------------------------------------------------------------------
__global__ void fused_scores_kernel(const float* __restrict__ enc,
                                    const float* __restrict__ Wh,
                                    const float* __restrict__ proj_s,
                                    const float* __restrict__ v,
                                    float* __restrict__ scores_part) {
    __shared__ __align__(16) unsigned short As[128][40];  // 32 cols + 8 pad
    __shared__ __align__(16) unsigned short Bs[128][40];
    __shared__ float sums[128][2];

    const int bx = blockIdx.x;
    const int nt = bx & 7;    // 8 N-tiles
    const int mt = bx >> 3;   // 512 M-tiles
    const int t = threadIdx.x;
    const int w = t >> 6, lane = t & 63;
    const int wr = w >> 1, wc = w & 1;
    const int lrow = lane & 15, lgrp = lane >> 4;

    f32x4 acc[4][4] = {};

    // staging assignment: thread owns 16 consecutive f32 of one row (A and B)
    const int srow = t >> 1;
    const int shalf = t & 1;
    const float* gA = enc + (size_t)(mt * 128 + srow) * H_ + shalf * 16;
    const float* gB = Wh  + (size_t)(nt * 128 + srow) * H_ + shalf * 16;
    unsigned short* lA = &As[srow][shalf * 16];
    unsigned short* lB = &Bs[srow][shalf * 16];

    for (int kt = 0; kt < H_ / 32; ++kt) {
        __syncthreads();   // previous compute done before overwrite
        const float4* a4 = (const float4*)(gA + kt * 32);
        const float4* b4 = (const float4*)(gB + kt * 32);
        union { unsigned short us[16]; uint4 q[2]; } pa, pb;
#pragma unroll
        for (int i = 0; i < 4; ++i) {
            float4 av = a4[i];
            float4 bv = b4[i];
            pa.us[i*4+0] = f2bf(av.x); pa.us[i*4+1] = f2bf(av.y);
            pa.us[i*4+2] = f2bf(av.z); pa.us[i*4+3] = f2bf(av.w);
            pb.us[i*4+0] = f2bf(bv.x); pb.us[i*4+1] = f2bf(bv.y);
            pb.us[i*4+2] = f2bf(bv.z); pb.us[i*4+3] = f2bf(bv.w);
        }
        *(uint4*)(lA)     = pa.q[0];
        *(uint4*)(lA + 8) = pa.q[1];
        *(uint4*)(lB)     = pb.q[0];
        *(uint4*)(lB + 8) = pb.q[1];
        __syncthreads();

        short8 af[4], bf[4];
#pragma unroll
        for (int m = 0; m < 4; ++m)
            af[m] = *(const short8*)&As[wr * 64 + m * 16 + lrow][lgrp * 8];
#pragma unroll
        for (int n = 0; n < 4; ++n)
            bf[n] = *(const short8*)&Bs[wc * 64 + n * 16 + lrow][lgrp * 8];
#pragma unroll
        for (int m = 0; m < 4; ++m)
#pragma unroll
            for (int n = 0; n < 4; ++n)
                acc[m][n] = __builtin_amdgcn_mfma_f32_16x16x32_bf16(af[m], bf[n], acc[m][n], 0, 0, 0);
    }

    // epilogue: val = tanh(proj + proj_s[b,col]); rowsum += val*v[col]
    const int b = mt >> 3;   // 8 M-tiles per batch row (S=1024, BM=128)
    float vv[4], ps[4];
#pragma unroll
    for (int n = 0; n < 4; ++n) {
        int col = nt * 128 + wc * 64 + n * 16 + lrow;
        vv[n] = v[col];
        ps[n] = proj_s[b * H_ + col];
    }
    float rs[4][4];
#pragma unroll
    for (int m = 0; m < 4; ++m) {
#pragma unroll
        for (int j = 0; j < 4; ++j) {
            float s = 0.0f;
#pragma unroll
            for (int n = 0; n < 4; ++n)
                s = fmaf(tanh_fast(acc[m][n][j] + ps[n]), vv[n], s);
            // reduce across the 16 lanes sharing this row (vary lane&15)
            s += __shfl_xor(s, 1, 64);
            s += __shfl_xor(s, 2, 64);
            s += __shfl_xor(s, 4, 64);
            s += __shfl_xor(s, 8, 64);
            rs[m][j] = s;
        }
    }
    if (lrow == 0) {
#pragma unroll
        for (int m = 0; m < 4; ++m)
#pragma unroll
            for (int j = 0; j < 4; ++j)
                sums[wr * 64 + m * 16 + lgrp * 4 + j][wc] = rs[m][j];
    }
    __syncthreads();
    if (t < 128)
        scores_part[(size_t)nt * M_ + mt * 128 + t] = sums[t][0] + sums[t][1];
}

// ---------------------------------------------------------------------------
// K3: softmax over S per batch row (sums the 8 N-tile partials first)
// ---------------------------------------------------------------------------
__global__ void softmax_kernel(const float* __restrict__ scores_part,
                               const int* __restrict__ mask,
                               float* __restrict__ weights) {
    const int b = blockIdx.x, t = threadIdx.x;
    __shared__ float red[8];
    float sc[4];
#pragma unroll
    for (int i = 0; i < 4; ++i) {
        int s = t + i * 256;
        float x = 0.0f;
#pragma unroll
        for (int p = 0; p < 8; ++p)
            x += scores_part[(size_t)p * M_ + b * S_ + s];
        if (mask[b * S_ + s] == 0) x = -INFINITY;
        sc[i] = x;
    }
    float mx = fmaxf(fmaxf(sc[0], sc[1]), fmaxf(sc[2], sc[3]));
#pragma unroll
    for (int m = 32; m >= 1; m >>= 1) mx = fmaxf(mx, __shfl_xor(mx, m, 64));
    if ((t & 63) == 0) red[t >> 6] = mx;
    __syncthreads();
    mx = fmaxf(fmaxf(red[0], red[1]), fmaxf(red[2], red[3]));

    float e[4]; float sum = 0.0f;
#pragma unroll
    for (int i = 0; i < 4; ++i) { e[i] = __expf(sc[i] - mx); sum += e[i]; }
#pragma unroll
    for (int m = 32; m >= 1; m >>= 1) sum += __shfl_xor(sum, m, 64);
    if ((t & 63) == 0) red[4 + (t >> 6)] = sum;
    __syncthreads();
    sum = red[4] + red[5] + red[6] + red[7];
    float inv = 1.0f / sum;
#pragma unroll
    for (int i = 0; i < 4; ++i)
        weights[b * S_ + t + i * 256] = e[i] * inv;
}

// ---------------------------------------------------------------------------
// K4: context partials over s-chunks: ctx_part[sc][b][h]
// ---------------------------------------------------------------------------
__global__ void context_part_kernel(const float* __restrict__ enc,
                                    const float* __restrict__ weights,
                                    float* __restrict__ ctx_part) {
    const int b = blockIdx.x >> 4;
    const int sc = blockIdx.x & 15;
    const int t = threadIdx.x;
    __shared__ float wv[64];
    if (t < 64) wv[t] = weights[b * S_ + sc * 64 + t];
    __syncthreads();
    const float4* e4 = (const float4*)(enc + (size_t)(b * S_ + sc * 64) * H_) + t;
    float ax = 0.f, ay = 0.f, az = 0.f, aw = 0.f;
#pragma unroll 4
    for (int i = 0; i < 64; ++i) {
        float4 ev = e4[i * 256];   // next s row = +1024 floats = +256 float4
        float wgt = wv[i];
        ax = fmaf(wgt, ev.x, ax);
        ay = fmaf(wgt, ev.y, ay);
        az = fmaf(wgt, ev.z, az);
        aw = fmaf(wgt, ev.w, aw);
    }
    float4 o; o.x = ax; o.y = ay; o.z = az; o.w = aw;
    *((float4*)(ctx_part + (size_t)sc * M_ + b * H_) + t) = o;
}

// ---------------------------------------------------------------------------
// K5: reduce the 16 context partials
// ---------------------------------------------------------------------------
__global__ void ctx_reduce_kernel(const float* __restrict__ ctx_part,
                                  float* __restrict__ ctx) {
    int idx = blockIdx.x * 256 + threadIdx.x;
    float s = 0.0f;
#pragma unroll
    for (int p = 0; p < 16; ++p) s += ctx_part[(size_t)p * M_ + idx];
    ctx[idx] = s;
}

extern "C" void kernel_launch(void* const* d_in, const int* in_sizes, int n_in,
                              void* d_out, int out_size, void* d_ws, size_t ws_size,
                              hipStream_t stream) {
    const float* dec  = (const float*)d_in[0];   // [B,H]
    const float* enc  = (const float*)d_in[1];   // [B,S,H]
    const int*   mask = (const int*)d_in[2];     // [B,S]
    const float* Ws   = (const float*)d_in[3];   // [H,H]
    const float* Wh   = (const float*)d_in[4];   // [H,H]
    const float* v    = (const float*)d_in[5];   // [H]

    float* out = (float*)d_out;          // [0:65536] context, [65536:131072] weights
    float* proj_s      = (float*)d_ws;              // 65536 f32
    float* scores_part = proj_s + M_;               // 8 * 65536 f32
    float* ctx_part    = scores_part + 8 * (size_t)M_;  // 16 * 65536 f32
    // total ws use: 25 * 65536 * 4 = 6.5 MB

    proj_s_kernel<<<256, 256, 0, stream>>>(dec, Ws, proj_s);
    fused_scores_kernel<<<4096, 256, 0, stream>>>(enc, Wh, proj_s, v, scores_part);
    softmax_kernel<<<64, 256, 0, stream>>>(scores_part, mask, out + M_);
    context_part_kernel<<<1024, 256, 0, stream>>>(enc, out + M_, ctx_part);
    ctx_reduce_kernel<<<256, 256, 0, stream>>>(ctx_part, out);
}

// Round 2
// 496.275 us; speedup vs baseline: 1.5129x; 1.5129x over previous
//
#include <hip/hip_runtime.h>
#include <hip/hip_bf16.h>

#define B_ 64
#define S_ 1024
#define H_ 1024
#define M_ (B_*S_)   // 65536 rows of the big GEMM

typedef __attribute__((ext_vector_type(8))) short short8;
typedef __attribute__((ext_vector_type(4))) float f32x4;

__device__ __forceinline__ unsigned short f2bf(float f) {
    union { float f; unsigned u; } c; c.f = f;
    unsigned u = c.u;
    unsigned r = (u + 0x7fffu + ((u >> 16) & 1u)) >> 16;  // RTNE, finite inputs
    return (unsigned short)r;
}

__device__ __forceinline__ float tanh_fast(float x) {
    float t = __expf(2.0f * x);                 // exp(2x)
    return 1.0f - 2.0f * __builtin_amdgcn_rcpf(t + 1.0f);  // inf-safe
}

// async global->LDS, 16B per lane. LDS dest = wave-uniform base + lane*16.
__device__ __forceinline__ void gll16(const unsigned short* g, unsigned short* l) {
    auto* gp = (const __attribute__((address_space(1))) unsigned short*)(g);
    auto* lp = (__attribute__((address_space(3))) unsigned short*)(l);
    __builtin_amdgcn_global_load_lds(gp, lp, 16, 0, 0);
}

// ---------------------------------------------------------------------------
// K0: f32 -> bf16 conversion (8 elems/thread/iter, 16B stores)
// ---------------------------------------------------------------------------
__global__ void cvt_bf16_kernel(const float* __restrict__ src,
                                unsigned short* __restrict__ dst, int n8) {
    int idx = blockIdx.x * blockDim.x + threadIdx.x;
    int stride = gridDim.x * blockDim.x;
    for (int i = idx; i < n8; i += stride) {
        const float4* s4 = (const float4*)src + (size_t)i * 2;
        float4 a = s4[0], b = s4[1];
        short8 o;
        o[0] = f2bf(a.x); o[1] = f2bf(a.y); o[2] = f2bf(a.z); o[3] = f2bf(a.w);
        o[4] = f2bf(b.x); o[5] = f2bf(b.y); o[6] = f2bf(b.z); o[7] = f2bf(b.w);
        *((short8*)dst + i) = o;
    }
}

// ---------------------------------------------------------------------------
// K1: proj_s[b,k] = sum_h dec[b,h] * W_s[k,h].  One wave per k-column.
// ---------------------------------------------------------------------------
__global__ void proj_s_kernel(const float* __restrict__ dec,
                              const float* __restrict__ Ws,
                              float* __restrict__ proj_s) {
    const int t = threadIdx.x;
    const int lane = t & 63;
    const int w = t >> 6;
    const int k = blockIdx.x * 4 + w;

    float acc[64];
#pragma unroll
    for (int b = 0; b < 64; ++b) acc[b] = 0.0f;

    for (int hc = 0; hc < 16; ++hc) {
        float wv = Ws[(size_t)k * H_ + hc * 64 + lane];
#pragma unroll
        for (int b = 0; b < 64; ++b)
            acc[b] = fmaf(dec[b * H_ + hc * 64 + lane], wv, acc[b]);
    }
#pragma unroll
    for (int m = 1; m < 64; m <<= 1) {
#pragma unroll
        for (int b = 0; b < 64; ++b)
            acc[b] += __shfl_xor(acc[b], m, 64);
    }
    float out = 0.0f;
#pragma unroll
    for (int b = 0; b < 64; ++b)
        if (lane == b) out = acc[b];
    proj_s[lane * H_ + k] = out;
}

// ---------------------------------------------------------------------------
// K2 fast: bf16 GEMM via global_load_lds (m97 structure) + tanh + v-dot.
// Tile 128x128, BK=32, 4 waves, linear LDS [128][32].
// ---------------------------------------------------------------------------
__global__ void fused_scores_bf16_kernel(const unsigned short* __restrict__ encb,
                                         const unsigned short* __restrict__ Whb,
                                         const float* __restrict__ proj_s,
                                         const float* __restrict__ v,
                                         float* __restrict__ scores_part) {
    __shared__ __align__(16) unsigned short AsF[128 * 32];
    __shared__ __align__(16) unsigned short BsF[128 * 32];
    __shared__ float sums[128][2];

    const int bx = blockIdx.x;
    const int nt = bx & 7;    // 8 N-tiles
    const int mt = bx >> 3;   // 512 M-tiles
    const int t = threadIdx.x;
    const int w = t >> 6, lane = t & 63;
    const int wr = w >> 1, wc = w & 1;
    const int lrow = lane & 15, lgrp = lane >> 4;

    f32x4 acc[4][4] = {};

    // staging: wave w owns rows [w*32, w*32+32); 2 issues of 1KB per operand.
    // issue i covers rows w*32+i*16 + (lane>>2), col halfwords (lane&3)*8.
    const int srow = lane >> 2;
    const int scol = (lane & 3) * 8;
    const unsigned short* gA0 = encb + (size_t)(mt * 128 + w * 32 + srow) * H_ + scol;
    const unsigned short* gA1 = gA0 + 16 * H_;
    const unsigned short* gB0 = Whb + (size_t)(nt * 128 + w * 32 + srow) * H_ + scol;
    const unsigned short* gB1 = gB0 + 16 * H_;
    unsigned short* lA0 = AsF + (w * 2 + 0) * 512;
    unsigned short* lA1 = AsF + (w * 2 + 1) * 512;
    unsigned short* lB0 = BsF + (w * 2 + 0) * 512;
    unsigned short* lB1 = BsF + (w * 2 + 1) * 512;

    for (int kt = 0; kt < H_ / 32; ++kt) {
        __syncthreads();   // previous compute done before overwrite
        gll16(gA0 + kt * 32, lA0);
        gll16(gA1 + kt * 32, lA1);
        gll16(gB0 + kt * 32, lB0);
        gll16(gB1 + kt * 32, lB1);
        __syncthreads();   // compiler drains vmcnt(0) before barrier

        short8 af[4], bf[4];
#pragma unroll
        for (int m = 0; m < 4; ++m)
            af[m] = *(const short8*)&AsF[(wr * 64 + m * 16 + lrow) * 32 + lgrp * 8];
#pragma unroll
        for (int n = 0; n < 4; ++n)
            bf[n] = *(const short8*)&BsF[(wc * 64 + n * 16 + lrow) * 32 + lgrp * 8];
#pragma unroll
        for (int m = 0; m < 4; ++m)
#pragma unroll
            for (int n = 0; n < 4; ++n)
                acc[m][n] = __builtin_amdgcn_mfma_f32_16x16x32_bf16(af[m], bf[n], acc[m][n], 0, 0, 0);
    }

    // epilogue: val = tanh(proj + proj_s[b,col]); rowsum += val*v[col]
    const int b = mt >> 3;   // 8 M-tiles per batch row
    float vv[4], ps[4];
#pragma unroll
    for (int n = 0; n < 4; ++n) {
        int col = nt * 128 + wc * 64 + n * 16 + lrow;
        vv[n] = v[col];
        ps[n] = proj_s[b * H_ + col];
    }
    float rs[4][4];
#pragma unroll
    for (int m = 0; m < 4; ++m) {
#pragma unroll
        for (int j = 0; j < 4; ++j) {
            float s = 0.0f;
#pragma unroll
            for (int n = 0; n < 4; ++n)
                s = fmaf(tanh_fast(acc[m][n][j] + ps[n]), vv[n], s);
            s += __shfl_xor(s, 1, 64);
            s += __shfl_xor(s, 2, 64);
            s += __shfl_xor(s, 4, 64);
            s += __shfl_xor(s, 8, 64);
            rs[m][j] = s;
        }
    }
    if (lrow == 0) {
#pragma unroll
        for (int m = 0; m < 4; ++m)
#pragma unroll
            for (int j = 0; j < 4; ++j)
                sums[wr * 64 + m * 16 + lgrp * 4 + j][wc] = rs[m][j];
    }
    __syncthreads();
    if (t < 128)
        scores_part[(size_t)nt * M_ + mt * 128 + t] = sums[t][0] + sums[t][1];
}

// ---------------------------------------------------------------------------
// K2 fallback: f32-input version (reg-staged conversion) — R0 kernel.
// ---------------------------------------------------------------------------
__global__ void fused_scores_kernel(const float* __restrict__ enc,
                                    const float* __restrict__ Wh,
                                    const float* __restrict__ proj_s,
                                    const float* __restrict__ v,
                                    float* __restrict__ scores_part) {
    __shared__ __align__(16) unsigned short As[128][40];
    __shared__ __align__(16) unsigned short Bs[128][40];
    __shared__ float sums[128][2];

    const int bx = blockIdx.x;
    const int nt = bx & 7;
    const int mt = bx >> 3;
    const int t = threadIdx.x;
    const int w = t >> 6, lane = t & 63;
    const int wr = w >> 1, wc = w & 1;
    const int lrow = lane & 15, lgrp = lane >> 4;

    f32x4 acc[4][4] = {};

    const int srow = t >> 1;
    const int shalf = t & 1;
    const float* gA = enc + (size_t)(mt * 128 + srow) * H_ + shalf * 16;
    const float* gB = Wh  + (size_t)(nt * 128 + srow) * H_ + shalf * 16;
    unsigned short* lA = &As[srow][shalf * 16];
    unsigned short* lB = &Bs[srow][shalf * 16];

    for (int kt = 0; kt < H_ / 32; ++kt) {
        __syncthreads();
        const float4* a4 = (const float4*)(gA + kt * 32);
        const float4* b4 = (const float4*)(gB + kt * 32);
        union { unsigned short us[16]; uint4 q[2]; } pa, pb;
#pragma unroll
        for (int i = 0; i < 4; ++i) {
            float4 av = a4[i];
            float4 bv = b4[i];
            pa.us[i*4+0] = f2bf(av.x); pa.us[i*4+1] = f2bf(av.y);
            pa.us[i*4+2] = f2bf(av.z); pa.us[i*4+3] = f2bf(av.w);
            pb.us[i*4+0] = f2bf(bv.x); pb.us[i*4+1] = f2bf(bv.y);
            pb.us[i*4+2] = f2bf(bv.z); pb.us[i*4+3] = f2bf(bv.w);
        }
        *(uint4*)(lA)     = pa.q[0];
        *(uint4*)(lA + 8) = pa.q[1];
        *(uint4*)(lB)     = pb.q[0];
        *(uint4*)(lB + 8) = pb.q[1];
        __syncthreads();

        short8 af[4], bf[4];
#pragma unroll
        for (int m = 0; m < 4; ++m)
            af[m] = *(const short8*)&As[wr * 64 + m * 16 + lrow][lgrp * 8];
#pragma unroll
        for (int n = 0; n < 4; ++n)
            bf[n] = *(const short8*)&Bs[wc * 64 + n * 16 + lrow][lgrp * 8];
#pragma unroll
        for (int m = 0; m < 4; ++m)
#pragma unroll
            for (int n = 0; n < 4; ++n)
                acc[m][n] = __builtin_amdgcn_mfma_f32_16x16x32_bf16(af[m], bf[n], acc[m][n], 0, 0, 0);
    }

    const int b = mt >> 3;
    float vv[4], ps[4];
#pragma unroll
    for (int n = 0; n < 4; ++n) {
        int col = nt * 128 + wc * 64 + n * 16 + lrow;
        vv[n] = v[col];
        ps[n] = proj_s[b * H_ + col];
    }
    float rs[4][4];
#pragma unroll
    for (int m = 0; m < 4; ++m) {
#pragma unroll
        for (int j = 0; j < 4; ++j) {
            float s = 0.0f;
#pragma unroll
            for (int n = 0; n < 4; ++n)
                s = fmaf(tanh_fast(acc[m][n][j] + ps[n]), vv[n], s);
            s += __shfl_xor(s, 1, 64);
            s += __shfl_xor(s, 2, 64);
            s += __shfl_xor(s, 4, 64);
            s += __shfl_xor(s, 8, 64);
            rs[m][j] = s;
        }
    }
    if (lrow == 0) {
#pragma unroll
        for (int m = 0; m < 4; ++m)
#pragma unroll
            for (int j = 0; j < 4; ++j)
                sums[wr * 64 + m * 16 + lgrp * 4 + j][wc] = rs[m][j];
    }
    __syncthreads();
    if (t < 128)
        scores_part[(size_t)nt * M_ + mt * 128 + t] = sums[t][0] + sums[t][1];
}

// ---------------------------------------------------------------------------
// K3: softmax over S per batch row
// ---------------------------------------------------------------------------
__global__ void softmax_kernel(const float* __restrict__ scores_part,
                               const int* __restrict__ mask,
                               float* __restrict__ weights) {
    const int b = blockIdx.x, t = threadIdx.x;
    __shared__ float red[8];
    float sc[4];
#pragma unroll
    for (int i = 0; i < 4; ++i) {
        int s = t + i * 256;
        float x = 0.0f;
#pragma unroll
        for (int p = 0; p < 8; ++p)
            x += scores_part[(size_t)p * M_ + b * S_ + s];
        if (mask[b * S_ + s] == 0) x = -INFINITY;
        sc[i] = x;
    }
    float mx = fmaxf(fmaxf(sc[0], sc[1]), fmaxf(sc[2], sc[3]));
#pragma unroll
    for (int m = 32; m >= 1; m >>= 1) mx = fmaxf(mx, __shfl_xor(mx, m, 64));
    if ((t & 63) == 0) red[t >> 6] = mx;
    __syncthreads();
    mx = fmaxf(fmaxf(red[0], red[1]), fmaxf(red[2], red[3]));

    float e[4]; float sum = 0.0f;
#pragma unroll
    for (int i = 0; i < 4; ++i) { e[i] = __expf(sc[i] - mx); sum += e[i]; }
#pragma unroll
    for (int m = 32; m >= 1; m >>= 1) sum += __shfl_xor(sum, m, 64);
    if ((t & 63) == 0) red[4 + (t >> 6)] = sum;
    __syncthreads();
    sum = red[4] + red[5] + red[6] + red[7];
    float inv = 1.0f / sum;
#pragma unroll
    for (int i = 0; i < 4; ++i)
        weights[b * S_ + t + i * 256] = e[i] * inv;
}

// ---------------------------------------------------------------------------
// K4: context partials over s-chunks: ctx_part[sc][b][h]
// ---------------------------------------------------------------------------
__global__ void context_part_kernel(const float* __restrict__ enc,
                                    const float* __restrict__ weights,
                                    float* __restrict__ ctx_part) {
    const int b = blockIdx.x >> 4;
    const int sc = blockIdx.x & 15;
    const int t = threadIdx.x;
    __shared__ float wv[64];
    if (t < 64) wv[t] = weights[b * S_ + sc * 64 + t];
    __syncthreads();
    const float4* e4 = (const float4*)(enc + (size_t)(b * S_ + sc * 64) * H_) + t;
    float ax = 0.f, ay = 0.f, az = 0.f, aw = 0.f;
#pragma unroll 4
    for (int i = 0; i < 64; ++i) {
        float4 ev = e4[i * 256];
        float wgt = wv[i];
        ax = fmaf(wgt, ev.x, ax);
        ay = fmaf(wgt, ev.y, ay);
        az = fmaf(wgt, ev.z, az);
        aw = fmaf(wgt, ev.w, aw);
    }
    float4 o; o.x = ax; o.y = ay; o.z = az; o.w = aw;
    *((float4*)(ctx_part + (size_t)sc * M_ + b * H_) + t) = o;
}

// ---------------------------------------------------------------------------
// K5: reduce the 16 context partials
// ---------------------------------------------------------------------------
__global__ void ctx_reduce_kernel(const float* __restrict__ ctx_part,
                                  float* __restrict__ ctx) {
    int idx = blockIdx.x * 256 + threadIdx.x;
    float s = 0.0f;
#pragma unroll
    for (int p = 0; p < 16; ++p) s += ctx_part[(size_t)p * M_ + idx];
    ctx[idx] = s;
}

extern "C" void kernel_launch(void* const* d_in, const int* in_sizes, int n_in,
                              void* d_out, int out_size, void* d_ws, size_t ws_size,
                              hipStream_t stream) {
    const float* dec  = (const float*)d_in[0];   // [B,H]
    const float* enc  = (const float*)d_in[1];   // [B,S,H]
    const int*   mask = (const int*)d_in[2];     // [B,S]
    const float* Ws   = (const float*)d_in[3];   // [H,H]
    const float* Wh   = (const float*)d_in[4];   // [H,H]
    const float* v    = (const float*)d_in[5];   // [H]

    float* out = (float*)d_out;          // [0:65536] context, [65536:131072] weights

    float* proj_s      = (float*)d_ws;                  // 65536 f32
    float* scores_part = proj_s + M_;                   // 8 * 65536 f32
    float* ctx_part    = scores_part + 8 * (size_t)M_;  // 16 * 65536 f32
    unsigned short* encb = (unsigned short*)(ctx_part + 16 * (size_t)M_);  // 67108864 bf16
    unsigned short* Whb  = encb + (size_t)B_ * S_ * H_;                     // 1048576 bf16

    const size_t need = 4ull * (M_ + 8ull * M_ + 16ull * M_)
                      + 2ull * ((size_t)B_ * S_ * H_ + (size_t)H_ * H_);

    proj_s_kernel<<<256, 256, 0, stream>>>(dec, Ws, proj_s);
    if (ws_size >= need) {
        cvt_bf16_kernel<<<2048, 256, 0, stream>>>(enc, encb, B_ * S_ * H_ / 8);
        cvt_bf16_kernel<<<512, 256, 0, stream>>>(Wh, Whb, H_ * H_ / 8);
        fused_scores_bf16_kernel<<<4096, 256, 0, stream>>>(encb, Whb, proj_s, v, scores_part);
    } else {
        fused_scores_kernel<<<4096, 256, 0, stream>>>(enc, Wh, proj_s, v, scores_part);
    }
    softmax_kernel<<<64, 256, 0, stream>>>(scores_part, mask, out + M_);
    context_part_kernel<<<1024, 256, 0, stream>>>(enc, out + M_, ctx_part);
    ctx_reduce_kernel<<<256, 256, 0, stream>>>(ctx_part, out);
}

// Round 3
// 277.367 us; speedup vs baseline: 2.7069x; 1.7892x over previous
//
#include <hip/hip_runtime.h>
#include <hip/hip_bf16.h>

#define B_ 64
#define S_ 1024
#define H_ 1024
#define M_ (B_*S_)   // 65536 rows of the big GEMM

typedef __attribute__((ext_vector_type(8))) short short8;
typedef __attribute__((ext_vector_type(4))) float f32x4;

__device__ __forceinline__ unsigned short f2bf(float f) {
    union { float f; unsigned u; } c; c.f = f;
    unsigned u = c.u;
    unsigned r = (u + 0x7fffu + ((u >> 16) & 1u)) >> 16;  // RTNE, finite inputs
    return (unsigned short)r;
}

__device__ __forceinline__ float bf2f(unsigned short h) {
    union { unsigned u; float f; } c; c.u = ((unsigned)h) << 16;
    return c.f;
}

__device__ __forceinline__ float tanh_fast(float x) {
    float t = __expf(2.0f * x);
    return 1.0f - 2.0f * __builtin_amdgcn_rcpf(t + 1.0f);  // inf-safe
}

// async global->LDS, 16B per lane. LDS dest = wave-uniform base + lane*16.
__device__ __forceinline__ void gll16(const unsigned short* g, unsigned short* l) {
    auto* gp = (const __attribute__((address_space(1))) unsigned short*)(g);
    auto* lp = (__attribute__((address_space(3))) unsigned short*)(l);
    __builtin_amdgcn_global_load_lds(gp, lp, 16, 0, 0);
}

// ---------------------------------------------------------------------------
// K0: f32 -> bf16 conversion (8 elems/thread/iter, 16B stores)
// ---------------------------------------------------------------------------
__global__ void cvt_bf16_kernel(const float* __restrict__ src,
                                unsigned short* __restrict__ dst, int n8) {
    int idx = blockIdx.x * blockDim.x + threadIdx.x;
    int stride = gridDim.x * blockDim.x;
    for (int i = idx; i < n8; i += stride) {
        const float4* s4 = (const float4*)src + (size_t)i * 2;
        float4 a = s4[0], b = s4[1];
        short8 o;
        o[0] = f2bf(a.x); o[1] = f2bf(a.y); o[2] = f2bf(a.z); o[3] = f2bf(a.w);
        o[4] = f2bf(b.x); o[5] = f2bf(b.y); o[6] = f2bf(b.z); o[7] = f2bf(b.w);
        *((short8*)dst + i) = o;
    }
}

// ---------------------------------------------------------------------------
// K1a: proj_s split-K partials. grid = 256 = (kt 16) x (hs 16), 256 thr.
// part[hs][b][k] = sum_{h in chunk} dec[b,h] * Ws[k,h]
// ---------------------------------------------------------------------------
__global__ void proj_s_part_kernel(const float* __restrict__ dec,
                                   const float* __restrict__ Ws,
                                   float* __restrict__ part) {
    __shared__ float wss[64][68];   // +4 pad: 16B-aligned rows, conflict-free reads
    const int kt = blockIdx.x & 15, hs = blockIdx.x >> 4;
    const int k0 = kt * 64, h0 = hs * 64;
    const int t = threadIdx.x;

    {   // stage Ws tile [64k][64h]
        const int r = t >> 2, c = (t & 3) * 16;
        const float4* src = (const float4*)(Ws + (size_t)(k0 + r) * H_ + h0 + c);
        float4 v0 = src[0], v1 = src[1], v2 = src[2], v3 = src[3];
        *(float4*)&wss[r][c + 0]  = v0;
        *(float4*)&wss[r][c + 4]  = v1;
        *(float4*)&wss[r][c + 8]  = v2;
        *(float4*)&wss[r][c + 12] = v3;
    }
    const int b = t >> 2, kq = t & 3;
    float4 dreg[16];
    const float4* dsrc = (const float4*)(dec + (size_t)b * H_ + h0);
#pragma unroll
    for (int i = 0; i < 16; ++i) dreg[i] = dsrc[i];
    __syncthreads();

    float acc[16] = {};
#pragma unroll
    for (int h4 = 0; h4 < 16; ++h4) {
        float4 d = dreg[h4];
#pragma unroll
        for (int j = 0; j < 16; ++j) {
            float4 wv = *(const float4*)&wss[kq + 4 * j][h4 * 4];
            acc[j] = fmaf(d.x, wv.x, acc[j]);
            acc[j] = fmaf(d.y, wv.y, acc[j]);
            acc[j] = fmaf(d.z, wv.z, acc[j]);
            acc[j] = fmaf(d.w, wv.w, acc[j]);
        }
    }
#pragma unroll
    for (int j = 0; j < 16; ++j)
        part[(size_t)hs * M_ + b * H_ + k0 + kq + 4 * j] = acc[j];
}

// K1b: reduce the 16 h-split partials
__global__ void proj_red_kernel(const float* __restrict__ part,
                                float* __restrict__ proj_s) {
    int i = blockIdx.x * 256 + threadIdx.x;
    float s = 0.0f;
#pragma unroll
    for (int p = 0; p < 16; ++p) s += part[(size_t)p * M_ + i];
    proj_s[i] = s;
}

// ---------------------------------------------------------------------------
// K2 fast: bf16 GEMM via global_load_lds (m97 structure) + tanh + v-dot.
// Tile 128x128, BK=32, 4 waves, linear LDS, XCD-aware block swizzle.
// ---------------------------------------------------------------------------
__global__ void fused_scores_bf16_kernel(const unsigned short* __restrict__ encb,
                                         const unsigned short* __restrict__ Whb,
                                         const float* __restrict__ proj_s,
                                         const float* __restrict__ v,
                                         float* __restrict__ scores_part) {
    __shared__ __align__(16) unsigned short AsF[128 * 32];
    __shared__ __align__(16) unsigned short BsF[128 * 32];
    __shared__ float sums[128][2];

    // XCD swizzle: 4096 blocks, 8 XCDs -> each XCD gets 64 consecutive mt
    const int bx0 = blockIdx.x;
    const int bx = (bx0 & 7) * 512 + (bx0 >> 3);
    const int nt = bx & 7;    // 8 N-tiles
    const int mt = bx >> 3;   // 512 M-tiles
    const int t = threadIdx.x;
    const int w = t >> 6, lane = t & 63;
    const int wr = w >> 1, wc = w & 1;
    const int lrow = lane & 15, lgrp = lane >> 4;

    f32x4 acc[4][4] = {};

    const int srow = lane >> 2;
    const int scol = (lane & 3) * 8;
    const unsigned short* gA0 = encb + (size_t)(mt * 128 + w * 32 + srow) * H_ + scol;
    const unsigned short* gA1 = gA0 + 16 * H_;
    const unsigned short* gB0 = Whb + (size_t)(nt * 128 + w * 32 + srow) * H_ + scol;
    const unsigned short* gB1 = gB0 + 16 * H_;
    unsigned short* lA0 = AsF + (w * 2 + 0) * 512;
    unsigned short* lA1 = AsF + (w * 2 + 1) * 512;
    unsigned short* lB0 = BsF + (w * 2 + 0) * 512;
    unsigned short* lB1 = BsF + (w * 2 + 1) * 512;

    for (int kt = 0; kt < H_ / 32; ++kt) {
        __syncthreads();
        gll16(gA0 + kt * 32, lA0);
        gll16(gA1 + kt * 32, lA1);
        gll16(gB0 + kt * 32, lB0);
        gll16(gB1 + kt * 32, lB1);
        __syncthreads();

        short8 af[4], bf[4];
#pragma unroll
        for (int m = 0; m < 4; ++m)
            af[m] = *(const short8*)&AsF[(wr * 64 + m * 16 + lrow) * 32 + lgrp * 8];
#pragma unroll
        for (int n = 0; n < 4; ++n)
            bf[n] = *(const short8*)&BsF[(wc * 64 + n * 16 + lrow) * 32 + lgrp * 8];
#pragma unroll
        for (int m = 0; m < 4; ++m)
#pragma unroll
            for (int n = 0; n < 4; ++n)
                acc[m][n] = __builtin_amdgcn_mfma_f32_16x16x32_bf16(af[m], bf[n], acc[m][n], 0, 0, 0);
    }

    const int b = mt >> 3;   // 8 M-tiles per batch row
    float vv[4], ps[4];
#pragma unroll
    for (int n = 0; n < 4; ++n) {
        int col = nt * 128 + wc * 64 + n * 16 + lrow;
        vv[n] = v[col];
        ps[n] = proj_s[b * H_ + col];
    }
    float rs[4][4];
#pragma unroll
    for (int m = 0; m < 4; ++m) {
#pragma unroll
        for (int j = 0; j < 4; ++j) {
            float s = 0.0f;
#pragma unroll
            for (int n = 0; n < 4; ++n)
                s = fmaf(tanh_fast(acc[m][n][j] + ps[n]), vv[n], s);
            s += __shfl_xor(s, 1, 64);
            s += __shfl_xor(s, 2, 64);
            s += __shfl_xor(s, 4, 64);
            s += __shfl_xor(s, 8, 64);
            rs[m][j] = s;
        }
    }
    if (lrow == 0) {
#pragma unroll
        for (int m = 0; m < 4; ++m)
#pragma unroll
            for (int j = 0; j < 4; ++j)
                sums[wr * 64 + m * 16 + lgrp * 4 + j][wc] = rs[m][j];
    }
    __syncthreads();
    if (t < 128)
        scores_part[(size_t)nt * M_ + mt * 128 + t] = sums[t][0] + sums[t][1];
}

// ---------------------------------------------------------------------------
// K2 fallback: f32-input version (reg-staged conversion).
// ---------------------------------------------------------------------------
__global__ void fused_scores_kernel(const float* __restrict__ enc,
                                    const float* __restrict__ Wh,
                                    const float* __restrict__ proj_s,
                                    const float* __restrict__ v,
                                    float* __restrict__ scores_part) {
    __shared__ __align__(16) unsigned short As[128][40];
    __shared__ __align__(16) unsigned short Bs[128][40];
    __shared__ float sums[128][2];

    const int bx = blockIdx.x;
    const int nt = bx & 7;
    const int mt = bx >> 3;
    const int t = threadIdx.x;
    const int w = t >> 6, lane = t & 63;
    const int wr = w >> 1, wc = w & 1;
    const int lrow = lane & 15, lgrp = lane >> 4;

    f32x4 acc[4][4] = {};

    const int srow = t >> 1;
    const int shalf = t & 1;
    const float* gA = enc + (size_t)(mt * 128 + srow) * H_ + shalf * 16;
    const float* gB = Wh  + (size_t)(nt * 128 + srow) * H_ + shalf * 16;
    unsigned short* lA = &As[srow][shalf * 16];
    unsigned short* lB = &Bs[srow][shalf * 16];

    for (int kt = 0; kt < H_ / 32; ++kt) {
        __syncthreads();
        const float4* a4 = (const float4*)(gA + kt * 32);
        const float4* b4 = (const float4*)(gB + kt * 32);
        union { unsigned short us[16]; uint4 q[2]; } pa, pb;
#pragma unroll
        for (int i = 0; i < 4; ++i) {
            float4 av = a4[i];
            float4 bv = b4[i];
            pa.us[i*4+0] = f2bf(av.x); pa.us[i*4+1] = f2bf(av.y);
            pa.us[i*4+2] = f2bf(av.z); pa.us[i*4+3] = f2bf(av.w);
            pb.us[i*4+0] = f2bf(bv.x); pb.us[i*4+1] = f2bf(bv.y);
            pb.us[i*4+2] = f2bf(bv.z); pb.us[i*4+3] = f2bf(bv.w);
        }
        *(uint4*)(lA)     = pa.q[0];
        *(uint4*)(lA + 8) = pa.q[1];
        *(uint4*)(lB)     = pb.q[0];
        *(uint4*)(lB + 8) = pb.q[1];
        __syncthreads();

        short8 af[4], bf[4];
#pragma unroll
        for (int m = 0; m < 4; ++m)
            af[m] = *(const short8*)&As[wr * 64 + m * 16 + lrow][lgrp * 8];
#pragma unroll
        for (int n = 0; n < 4; ++n)
            bf[n] = *(const short8*)&Bs[wc * 64 + n * 16 + lrow][lgrp * 8];
#pragma unroll
        for (int m = 0; m < 4; ++m)
#pragma unroll
            for (int n = 0; n < 4; ++n)
                acc[m][n] = __builtin_amdgcn_mfma_f32_16x16x32_bf16(af[m], bf[n], acc[m][n], 0, 0, 0);
    }

    const int b = mt >> 3;
    float vv[4], ps[4];
#pragma unroll
    for (int n = 0; n < 4; ++n) {
        int col = nt * 128 + wc * 64 + n * 16 + lrow;
        vv[n] = v[col];
        ps[n] = proj_s[b * H_ + col];
    }
    float rs[4][4];
#pragma unroll
    for (int m = 0; m < 4; ++m) {
#pragma unroll
        for (int j = 0; j < 4; ++j) {
            float s = 0.0f;
#pragma unroll
            for (int n = 0; n < 4; ++n)
                s = fmaf(tanh_fast(acc[m][n][j] + ps[n]), vv[n], s);
            s += __shfl_xor(s, 1, 64);
            s += __shfl_xor(s, 2, 64);
            s += __shfl_xor(s, 4, 64);
            s += __shfl_xor(s, 8, 64);
            rs[m][j] = s;
        }
    }
    if (lrow == 0) {
#pragma unroll
        for (int m = 0; m < 4; ++m)
#pragma unroll
            for (int j = 0; j < 4; ++j)
                sums[wr * 64 + m * 16 + lgrp * 4 + j][wc] = rs[m][j];
    }
    __syncthreads();
    if (t < 128)
        scores_part[(size_t)nt * M_ + mt * 128 + t] = sums[t][0] + sums[t][1];
}

// ---------------------------------------------------------------------------
// K3: softmax over S per batch row
// ---------------------------------------------------------------------------
__global__ void softmax_kernel(const float* __restrict__ scores_part,
                               const int* __restrict__ mask,
                               float* __restrict__ weights) {
    const int b = blockIdx.x, t = threadIdx.x;
    __shared__ float red[8];
    float sc[4];
#pragma unroll
    for (int i = 0; i < 4; ++i) {
        int s = t + i * 256;
        float x = 0.0f;
#pragma unroll
        for (int p = 0; p < 8; ++p)
            x += scores_part[(size_t)p * M_ + b * S_ + s];
        if (mask[b * S_ + s] == 0) x = -INFINITY;
        sc[i] = x;
    }
    float mx = fmaxf(fmaxf(sc[0], sc[1]), fmaxf(sc[2], sc[3]));
#pragma unroll
    for (int m = 32; m >= 1; m >>= 1) mx = fmaxf(mx, __shfl_xor(mx, m, 64));
    if ((t & 63) == 0) red[t >> 6] = mx;
    __syncthreads();
    mx = fmaxf(fmaxf(red[0], red[1]), fmaxf(red[2], red[3]));

    float e[4]; float sum = 0.0f;
#pragma unroll
    for (int i = 0; i < 4; ++i) { e[i] = __expf(sc[i] - mx); sum += e[i]; }
#pragma unroll
    for (int m = 32; m >= 1; m >>= 1) sum += __shfl_xor(sum, m, 64);
    if ((t & 63) == 0) red[4 + (t >> 6)] = sum;
    __syncthreads();
    sum = red[4] + red[5] + red[6] + red[7];
    float inv = 1.0f / sum;
#pragma unroll
    for (int i = 0; i < 4; ++i)
        weights[b * S_ + t + i * 256] = e[i] * inv;
}

// ---------------------------------------------------------------------------
// K4 fast: context partials reading bf16 enc. grid = 2048 = b(64) x sc(32),
// 128 threads; thread owns 8 h over 32 s-rows.
// ---------------------------------------------------------------------------
__global__ void context_part_bf16_kernel(const unsigned short* __restrict__ encb,
                                         const float* __restrict__ weights,
                                         float* __restrict__ ctx_part) {
    const int b = blockIdx.x >> 5;
    const int sc = blockIdx.x & 31;
    const int t = threadIdx.x;   // 0..127
    __shared__ float wv[32];
    if (t < 32) wv[t] = weights[b * S_ + sc * 32 + t];
    __syncthreads();
    const short8* e8 = (const short8*)(encb + (size_t)(b * S_ + sc * 32) * H_) + t;
    float a[8] = {};
#pragma unroll 4
    for (int i = 0; i < 32; ++i) {
        short8 ev = e8[(size_t)i * 128];   // next s row = 1024 halfs = 128 short8
        float w = wv[i];
#pragma unroll
        for (int j = 0; j < 8; ++j)
            a[j] = fmaf(w, bf2f((unsigned short)ev[j]), a[j]);
    }
    float* dst = ctx_part + (size_t)sc * M_ + b * H_ + t * 8;
    float4 o0; o0.x = a[0]; o0.y = a[1]; o0.z = a[2]; o0.w = a[3];
    float4 o1; o1.x = a[4]; o1.y = a[5]; o1.z = a[6]; o1.w = a[7];
    *(float4*)dst = o0;
    *(float4*)(dst + 4) = o1;
}

// K4 fallback: f32 context partials (16 s-chunks)
__global__ void context_part_kernel(const float* __restrict__ enc,
                                    const float* __restrict__ weights,
                                    float* __restrict__ ctx_part) {
    const int b = blockIdx.x >> 4;
    const int sc = blockIdx.x & 15;
    const int t = threadIdx.x;
    __shared__ float wv[64];
    if (t < 64) wv[t] = weights[b * S_ + sc * 64 + t];
    __syncthreads();
    const float4* e4 = (const float4*)(enc + (size_t)(b * S_ + sc * 64) * H_) + t;
    float ax = 0.f, ay = 0.f, az = 0.f, aw = 0.f;
#pragma unroll 4
    for (int i = 0; i < 64; ++i) {
        float4 ev = e4[i * 256];
        float wgt = wv[i];
        ax = fmaf(wgt, ev.x, ax);
        ay = fmaf(wgt, ev.y, ay);
        az = fmaf(wgt, ev.z, az);
        aw = fmaf(wgt, ev.w, aw);
    }
    float4 o; o.x = ax; o.y = ay; o.z = az; o.w = aw;
    *((float4*)(ctx_part + (size_t)sc * M_ + b * H_) + t) = o;
}

// ---------------------------------------------------------------------------
// K5: reduce np context partials
// ---------------------------------------------------------------------------
__global__ void ctx_reduce_kernel(const float* __restrict__ ctx_part,
                                  float* __restrict__ ctx, int np) {
    int idx = blockIdx.x * 256 + threadIdx.x;
    float s = 0.0f;
    for (int p = 0; p < np; ++p) s += ctx_part[(size_t)p * M_ + idx];
    ctx[idx] = s;
}

extern "C" void kernel_launch(void* const* d_in, const int* in_sizes, int n_in,
                              void* d_out, int out_size, void* d_ws, size_t ws_size,
                              hipStream_t stream) {
    const float* dec  = (const float*)d_in[0];   // [B,H]
    const float* enc  = (const float*)d_in[1];   // [B,S,H]
    const int*   mask = (const int*)d_in[2];     // [B,S]
    const float* Ws   = (const float*)d_in[3];   // [H,H]
    const float* Wh   = (const float*)d_in[4];   // [H,H]
    const float* v    = (const float*)d_in[5];   // [H]

    float* out = (float*)d_out;          // [0:65536] context, [65536:131072] weights

    float* proj_s      = (float*)d_ws;                   // 65536 f32
    float* proj_part   = proj_s + M_;                    // 16 * 65536 f32
    float* scores_part = proj_part + 16 * (size_t)M_;    // 8 * 65536 f32
    float* ctx_part    = scores_part + 8 * (size_t)M_;   // 32 * 65536 f32
    unsigned short* encb = (unsigned short*)(ctx_part + 32 * (size_t)M_);  // 64M bf16
    unsigned short* Whb  = encb + (size_t)B_ * S_ * H_;                    // 1M bf16

    const size_t need_small = 4ull * (1 + 16 + 8 + 32) * M_;
    const size_t need_big   = need_small + 2ull * ((size_t)B_ * S_ * H_ + (size_t)H_ * H_);

    proj_s_part_kernel<<<256, 256, 0, stream>>>(dec, Ws, proj_part);
    proj_red_kernel<<<256, 256, 0, stream>>>(proj_part, proj_s);

    if (ws_size >= need_big) {
        cvt_bf16_kernel<<<2048, 256, 0, stream>>>(enc, encb, B_ * S_ * H_ / 8);
        cvt_bf16_kernel<<<512, 256, 0, stream>>>(Wh, Whb, H_ * H_ / 8);
        fused_scores_bf16_kernel<<<4096, 256, 0, stream>>>(encb, Whb, proj_s, v, scores_part);
        softmax_kernel<<<64, 256, 0, stream>>>(scores_part, mask, out + M_);
        context_part_bf16_kernel<<<2048, 128, 0, stream>>>(encb, out + M_, ctx_part);
        ctx_reduce_kernel<<<256, 256, 0, stream>>>(ctx_part, out, 32);
    } else {
        fused_scores_kernel<<<4096, 256, 0, stream>>>(enc, Wh, proj_s, v, scores_part);
        softmax_kernel<<<64, 256, 0, stream>>>(scores_part, mask, out + M_);
        context_part_kernel<<<1024, 256, 0, stream>>>(enc, out + M_, ctx_part);
        ctx_reduce_kernel<<<256, 256, 0, stream>>>(ctx_part, out, 16);
    }
}